// Round 1
// baseline (753.283 us; speedup 1.0000x reference)
//
#include <hip/hip_runtime.h>
#include <hip/hip_bf16.h>
#include <stdint.h>

// out = A_sparse @ (X @ W) + b
// Phase 1: CSR build (hist -> scan -> permute), int atomics only.
// Phase 2: XW = X @ W  (fp32 tiled GEMM).
// Phase 3: per-node wave gathers XW[col] rows (coalesced float4), + bias, one store.

#define D 256  // D_IN == D_OUT == 256

// ---------------- CSR build ----------------

__global__ void hist_kernel(const int* __restrict__ row, int* __restrict__ counts, int E) {
    int e = blockIdx.x * 256 + threadIdx.x;
    if (e < E) atomicAdd(&counts[row[e]], 1);
}

__global__ void block_sums_kernel(const int* __restrict__ counts, int* __restrict__ partials, int M) {
    __shared__ int s[256];
    int i = blockIdx.x * 256 + threadIdx.x;
    s[threadIdx.x] = (i < M) ? counts[i] : 0;
    __syncthreads();
    for (int off = 128; off > 0; off >>= 1) {
        if (threadIdx.x < off) s[threadIdx.x] += s[threadIdx.x + off];
        __syncthreads();
    }
    if (threadIdx.x == 0) partials[blockIdx.x] = s[0];
}

// exclusive scan of partials[0..NB) in place, single block
__global__ void scan_partials_kernel(int* __restrict__ partials, int NB) {
    __shared__ int buf[256];
    __shared__ int carry_s;
    if (threadIdx.x == 0) carry_s = 0;
    __syncthreads();
    for (int base = 0; base < NB; base += 256) {
        int i = base + threadIdx.x;
        int v = (i < NB) ? partials[i] : 0;
        buf[threadIdx.x] = v;
        __syncthreads();
        #pragma unroll
        for (int off = 1; off < 256; off <<= 1) {
            int t = (threadIdx.x >= off) ? buf[threadIdx.x - off] : 0;
            __syncthreads();
            buf[threadIdx.x] += t;
            __syncthreads();
        }
        int incl = buf[threadIdx.x];
        if (i < NB) partials[i] = carry_s + incl - v;  // exclusive
        __syncthreads();
        if (threadIdx.x == 0) carry_s += buf[255];
        __syncthreads();
    }
}

__global__ void scan_local_kernel(const int* __restrict__ counts, const int* __restrict__ partials,
                                  int* __restrict__ offsets, int* __restrict__ cursor, int M) {
    __shared__ int buf[256];
    int i = blockIdx.x * 256 + threadIdx.x;
    int v = (i < M) ? counts[i] : 0;
    buf[threadIdx.x] = v;
    __syncthreads();
    #pragma unroll
    for (int off = 1; off < 256; off <<= 1) {
        int t = (threadIdx.x >= off) ? buf[threadIdx.x - off] : 0;
        __syncthreads();
        buf[threadIdx.x] += t;
        __syncthreads();
    }
    int excl = partials[blockIdx.x] + buf[threadIdx.x] - v;
    if (i < M) { offsets[i] = excl; cursor[i] = excl; }
    if (i == M - 1) offsets[M] = excl + v;
}

__global__ void permute_kernel(const int* __restrict__ row, const int* __restrict__ col,
                               const float* __restrict__ val, int* __restrict__ cursor,
                               int* __restrict__ scol, float* __restrict__ sval, int E) {
    int e = blockIdx.x * 256 + threadIdx.x;
    if (e < E) {
        int r = row[e];
        int pos = atomicAdd(&cursor[r], 1);
        scol[pos] = col[e];
        sval[pos] = val[e];
    }
}

// ---------------- Dense GEMM: XW = X @ W ----------------
// BM=64, BN=64, BK=16; 256 threads (16x16), 4x4 register tile per thread.

__global__ __launch_bounds__(256) void gemm_xw_kernel(const float* __restrict__ A,
                                                      const float* __restrict__ B,
                                                      float* __restrict__ C, int M) {
    __shared__ float As[16][65];  // [k][row], +1 pad
    __shared__ float Bs[16][64];  // [k][col]
    const int tid = threadIdx.x;
    const int tx = tid & 15, ty = tid >> 4;
    const int row0 = blockIdx.x * 64;
    const int col0 = blockIdx.y * 64;

    float acc[4][4] = {};

    for (int k0 = 0; k0 < D; k0 += 16) {
        #pragma unroll
        for (int i = 0; i < 4; ++i) {
            int idx = tid + i * 256;           // 0..1023 over 64x16 tile
            int r = idx >> 4, k = idx & 15;
            int gr = row0 + r;
            As[k][r] = (gr < M) ? A[(size_t)gr * D + k0 + k] : 0.f;
        }
        #pragma unroll
        for (int i = 0; i < 4; ++i) {
            int idx = tid + i * 256;           // 0..1023 over 16x64 tile
            int r = idx >> 6, c = idx & 63;
            Bs[r][c] = B[(size_t)(k0 + r) * D + col0 + c];
        }
        __syncthreads();
        #pragma unroll
        for (int k = 0; k < 16; ++k) {
            float a[4], b[4];
            #pragma unroll
            for (int i = 0; i < 4; ++i) a[i] = As[k][ty * 4 + i];
            #pragma unroll
            for (int j = 0; j < 4; ++j) b[j] = Bs[k][tx * 4 + j];
            #pragma unroll
            for (int i = 0; i < 4; ++i)
                #pragma unroll
                for (int j = 0; j < 4; ++j)
                    acc[i][j] += a[i] * b[j];
        }
        __syncthreads();
    }

    #pragma unroll
    for (int i = 0; i < 4; ++i) {
        int gr = row0 + ty * 4 + i;
        if (gr < M) {
            float4 o = make_float4(acc[i][0], acc[i][1], acc[i][2], acc[i][3]);
            *(float4*)(C + (size_t)gr * D + col0 + tx * 4) = o;
        }
    }
}

// ---------------- Gather: out[r] = bias + sum_e val_e * XW[col_e] ----------------
// One wave (64 lanes) per node; lane l owns float4 at dim 4l.

__global__ __launch_bounds__(256) void gather_kernel(const float* __restrict__ XW,
                                                     const int* __restrict__ offsets,
                                                     const int* __restrict__ scol,
                                                     const float* __restrict__ sval,
                                                     const float* __restrict__ bias,
                                                     float* __restrict__ out, int M) {
    int wave = (int)((blockIdx.x * (size_t)blockDim.x + threadIdx.x) >> 6);
    int lane = threadIdx.x & 63;
    if (wave >= M) return;
    int beg = offsets[wave], end = offsets[wave + 1];
    float4 acc = make_float4(0.f, 0.f, 0.f, 0.f);
    for (int e = beg; e < end; ++e) {
        int c = scol[e];          // wave-uniform -> scalar load
        float v = sval[e];        // wave-uniform -> scalar load
        float4 x = *(const float4*)(XW + (size_t)c * D + lane * 4);
        acc.x += v * x.x; acc.y += v * x.y; acc.z += v * x.z; acc.w += v * x.w;
    }
    float4 b = *(const float4*)(bias + lane * 4);
    acc.x += b.x; acc.y += b.y; acc.z += b.z; acc.w += b.w;
    *(float4*)(out + (size_t)wave * D + lane * 4) = acc;
}

extern "C" void kernel_launch(void* const* d_in, const int* in_sizes, int n_in,
                              void* d_out, int out_size, void* d_ws, size_t ws_size,
                              hipStream_t stream) {
    const float* X    = (const float*)d_in[0];
    const int*   erow = (const int*)d_in[1];
    const int*   ecol = (const int*)d_in[2];
    const float* eval = (const float*)d_in[3];
    const float* W    = (const float*)d_in[4];
    const float* bias = (const float*)d_in[5];
    float* out = (float*)d_out;

    const int M = in_sizes[0] / D;   // 100000
    const int E = in_sizes[1];       // 1600000
    const int NB = (M + 255) / 256;  // 391

    // workspace carve (~117 MB)
    char* p = (char*)d_ws;
    float* XW = (float*)p;      p += (size_t)M * D * sizeof(float);
    int* counts = (int*)p;      p += (size_t)M * sizeof(int);
    int* offsets = (int*)p;     p += (size_t)(M + 1) * sizeof(int);
    int* cursor = (int*)p;      p += (size_t)M * sizeof(int);
    int* partials = (int*)p;    p += (size_t)NB * sizeof(int);
    p = (char*)(((uintptr_t)p + 15) & ~(uintptr_t)15);
    int* scol = (int*)p;        p += (size_t)E * sizeof(int);
    float* sval = (float*)p;    p += (size_t)E * sizeof(float);

    hipMemsetAsync(counts, 0, (size_t)M * sizeof(int), stream);
    hist_kernel<<<(E + 255) / 256, 256, 0, stream>>>(erow, counts, E);
    block_sums_kernel<<<NB, 256, 0, stream>>>(counts, partials, M);
    scan_partials_kernel<<<1, 256, 0, stream>>>(partials, NB);
    scan_local_kernel<<<NB, 256, 0, stream>>>(counts, partials, offsets, cursor, M);
    permute_kernel<<<(E + 255) / 256, 256, 0, stream>>>(erow, ecol, eval, cursor, scol, sval, E);

    dim3 ggrid((M + 63) / 64, D / 64);
    gemm_xw_kernel<<<ggrid, 256, 0, stream>>>(X, W, XW, M);

    gather_kernel<<<(int)(((size_t)M * 64 + 255) / 256), 256, 0, stream>>>(
        XW, offsets, scol, sval, bias, out, M);
}

// Round 2
// 523.360 us; speedup vs baseline: 1.4393x; 1.4393x over previous
//
#include <hip/hip_runtime.h>
#include <hip/hip_bf16.h>
#include <stdint.h>

// out = A_sparse @ (X @ W) + b
// Phase 1: CSR build (hist -> scan -> permute), int atomics only.
// Phase 2: convert X -> bf16, W -> bf16 transposed (Wt[n][k]).
// Phase 3: XWb = Xb @ W  via MFMA 16x16x32 bf16, output stored bf16.
// Phase 4: per-node wave gathers bf16 XWb[col] rows (8B/lane), fp32 accum, +bias, fp32 out.

#define D 256  // D_IN == D_OUT == 256

typedef __attribute__((ext_vector_type(8))) short bf16x8;
typedef __attribute__((ext_vector_type(4))) float f32x4;

__device__ __forceinline__ unsigned short f32_to_bf16(float f) {
    union { float f; unsigned int u; } x; x.f = f;
    unsigned int u = x.u;
    u += 0x7fffu + ((u >> 16) & 1u);   // round-to-nearest-even
    return (unsigned short)(u >> 16);
}
__device__ __forceinline__ float bf16_to_f32(unsigned short h) {
    union { unsigned int u; float f; } x; x.u = ((unsigned int)h) << 16;
    return x.f;
}

// ---------------- CSR build ----------------

__global__ void hist_kernel(const int* __restrict__ row, int* __restrict__ counts, int E) {
    int e = blockIdx.x * 256 + threadIdx.x;
    if (e < E) atomicAdd(&counts[row[e]], 1);
}

__global__ void block_sums_kernel(const int* __restrict__ counts, int* __restrict__ partials, int M) {
    __shared__ int s[256];
    int i = blockIdx.x * 256 + threadIdx.x;
    s[threadIdx.x] = (i < M) ? counts[i] : 0;
    __syncthreads();
    for (int off = 128; off > 0; off >>= 1) {
        if (threadIdx.x < off) s[threadIdx.x] += s[threadIdx.x + off];
        __syncthreads();
    }
    if (threadIdx.x == 0) partials[blockIdx.x] = s[0];
}

__global__ void scan_partials_kernel(int* __restrict__ partials, int NB) {
    __shared__ int buf[256];
    __shared__ int carry_s;
    if (threadIdx.x == 0) carry_s = 0;
    __syncthreads();
    for (int base = 0; base < NB; base += 256) {
        int i = base + threadIdx.x;
        int v = (i < NB) ? partials[i] : 0;
        buf[threadIdx.x] = v;
        __syncthreads();
        #pragma unroll
        for (int off = 1; off < 256; off <<= 1) {
            int t = (threadIdx.x >= off) ? buf[threadIdx.x - off] : 0;
            __syncthreads();
            buf[threadIdx.x] += t;
            __syncthreads();
        }
        int incl = buf[threadIdx.x];
        if (i < NB) partials[i] = carry_s + incl - v;  // exclusive
        __syncthreads();
        if (threadIdx.x == 0) carry_s += buf[255];
        __syncthreads();
    }
}

__global__ void scan_local_kernel(const int* __restrict__ counts, const int* __restrict__ partials,
                                  int* __restrict__ offsets, int* __restrict__ cursor, int M) {
    __shared__ int buf[256];
    int i = blockIdx.x * 256 + threadIdx.x;
    int v = (i < M) ? counts[i] : 0;
    buf[threadIdx.x] = v;
    __syncthreads();
    #pragma unroll
    for (int off = 1; off < 256; off <<= 1) {
        int t = (threadIdx.x >= off) ? buf[threadIdx.x - off] : 0;
        __syncthreads();
        buf[threadIdx.x] += t;
        __syncthreads();
    }
    int excl = partials[blockIdx.x] + buf[threadIdx.x] - v;
    if (i < M) { offsets[i] = excl; cursor[i] = excl; }
    if (i == M - 1) offsets[M] = excl + v;
}

__global__ void permute_kernel(const int* __restrict__ row, const int* __restrict__ col,
                               const float* __restrict__ val, int* __restrict__ cursor,
                               int* __restrict__ scol, float* __restrict__ sval, int E) {
    int e = blockIdx.x * 256 + threadIdx.x;
    if (e < E) {
        int r = row[e];
        int pos = atomicAdd(&cursor[r], 1);
        scol[pos] = col[e];
        sval[pos] = val[e];
    }
}

// ---------------- Conversions ----------------

// X (fp32, M*256) -> Xb (bf16). 4 elems/thread.
__global__ __launch_bounds__(256) void convert_x_kernel(const float* __restrict__ X,
                                                        unsigned short* __restrict__ Xb, int n4) {
    int i = blockIdx.x * 256 + threadIdx.x;
    if (i >= n4) return;
    float4 v = ((const float4*)X)[i];
    ushort4 o;
    o.x = f32_to_bf16(v.x); o.y = f32_to_bf16(v.y);
    o.z = f32_to_bf16(v.z); o.w = f32_to_bf16(v.w);
    ((ushort4*)Xb)[i] = o;
}

// W (fp32 [k][n]) -> Wt (bf16 [n][k])
__global__ __launch_bounds__(256) void convert_wt_kernel(const float* __restrict__ W,
                                                         unsigned short* __restrict__ Wt) {
    int i = blockIdx.x * 256 + threadIdx.x;   // i = n*256 + k
    int n = i >> 8, k = i & 255;
    Wt[i] = f32_to_bf16(W[k * 256 + n]);
}

// ---------------- MFMA GEMM: XWb = Xb @ W  (bf16 in, bf16 out) ----------------
// BM=128, BN=128, BK=32. 256 threads = 4 waves in 2x2; each wave: 4x4 grid of 16x16 tiles.
// LDS rows padded to 40 bf16 (80B) -> 2-way bank aliasing (free).

__global__ __launch_bounds__(256) void gemm_mfma_kernel(const unsigned short* __restrict__ Xb,
                                                        const unsigned short* __restrict__ Wt,
                                                        unsigned short* __restrict__ XWb, int M) {
    __shared__ unsigned short As[128 * 40];  // [m][k] padded
    __shared__ unsigned short Bs[128 * 40];  // [n][k] padded

    const int tid = threadIdx.x;
    const int wave = tid >> 6, lane = tid & 63;
    const int quad = lane >> 4, r = lane & 15;
    const int wm = (wave & 1) * 64, wn = (wave >> 1) * 64;
    const int m0 = blockIdx.x * 128;
    const int n0 = blockIdx.y * 128;

    const int srow = tid >> 2;        // 0..63, staging row
    const int sseg = tid & 3;         // 16B segment within 32-k row

    f32x4 acc[4][4] = {};

    for (int k0 = 0; k0 < D; k0 += 32) {
        // stage A: 128 rows x 32 k (two halves of 64 rows)
        #pragma unroll
        for (int h = 0; h < 2; ++h) {
            int row = srow + h * 64;
            int gm = m0 + row;
            uint4 v = make_uint4(0u, 0u, 0u, 0u);
            if (gm < M) v = *(const uint4*)(Xb + (size_t)gm * D + k0 + sseg * 8);
            *(uint4*)(&As[row * 40 + sseg * 8]) = v;
        }
        // stage B: 128 n-rows x 32 k from Wt
        #pragma unroll
        for (int h = 0; h < 2; ++h) {
            int row = srow + h * 64;
            uint4 v = *(const uint4*)(Wt + (size_t)(n0 + row) * D + k0 + sseg * 8);
            *(uint4*)(&Bs[row * 40 + sseg * 8]) = v;
        }
        __syncthreads();

        bf16x8 a[4], b[4];
        #pragma unroll
        for (int mt = 0; mt < 4; ++mt)
            a[mt] = *(const bf16x8*)(&As[(wm + mt * 16 + r) * 40 + quad * 8]);
        #pragma unroll
        for (int nt = 0; nt < 4; ++nt)
            b[nt] = *(const bf16x8*)(&Bs[(wn + nt * 16 + r) * 40 + quad * 8]);
        #pragma unroll
        for (int mt = 0; mt < 4; ++mt)
            #pragma unroll
            for (int nt = 0; nt < 4; ++nt)
                acc[mt][nt] = __builtin_amdgcn_mfma_f32_16x16x32_bf16(a[mt], b[nt], acc[mt][nt], 0, 0, 0);
        __syncthreads();
    }

    // epilogue: C[row=quad*4+reg][col=lane&15] per 16x16 tile
    #pragma unroll
    for (int mt = 0; mt < 4; ++mt) {
        #pragma unroll
        for (int reg = 0; reg < 4; ++reg) {
            int gm = m0 + wm + mt * 16 + quad * 4 + reg;
            if (gm < M) {
                #pragma unroll
                for (int nt = 0; nt < 4; ++nt) {
                    int gn = n0 + wn + nt * 16 + r;
                    XWb[(size_t)gm * D + gn] = f32_to_bf16(acc[mt][nt][reg]);
                }
            }
        }
    }
}

// ---------------- Gather: out[node] = bias + sum_e val_e * XWb[col_e] ----------------
// One wave per node; lane owns 4 bf16 dims (8B load per edge).

__global__ __launch_bounds__(256) void gather_kernel(const unsigned short* __restrict__ XWb,
                                                     const int* __restrict__ offsets,
                                                     const int* __restrict__ scol,
                                                     const float* __restrict__ sval,
                                                     const float* __restrict__ bias,
                                                     float* __restrict__ out, int M) {
    int node = (int)((blockIdx.x * (size_t)blockDim.x + threadIdx.x) >> 6);
    int lane = threadIdx.x & 63;
    if (node >= M) return;
    int beg = offsets[node], end = offsets[node + 1];
    float4 acc = make_float4(0.f, 0.f, 0.f, 0.f);
    int e = beg;
    for (; e + 1 < end; e += 2) {
        int c0 = scol[e], c1 = scol[e + 1];
        float v0 = sval[e], v1 = sval[e + 1];
        ushort4 x0 = *(const ushort4*)(XWb + (size_t)c0 * D + lane * 4);
        ushort4 x1 = *(const ushort4*)(XWb + (size_t)c1 * D + lane * 4);
        acc.x += v0 * bf16_to_f32(x0.x); acc.y += v0 * bf16_to_f32(x0.y);
        acc.z += v0 * bf16_to_f32(x0.z); acc.w += v0 * bf16_to_f32(x0.w);
        acc.x += v1 * bf16_to_f32(x1.x); acc.y += v1 * bf16_to_f32(x1.y);
        acc.z += v1 * bf16_to_f32(x1.z); acc.w += v1 * bf16_to_f32(x1.w);
    }
    if (e < end) {
        int c = scol[e];
        float v = sval[e];
        ushort4 x = *(const ushort4*)(XWb + (size_t)c * D + lane * 4);
        acc.x += v * bf16_to_f32(x.x); acc.y += v * bf16_to_f32(x.y);
        acc.z += v * bf16_to_f32(x.z); acc.w += v * bf16_to_f32(x.w);
    }
    float4 b = *(const float4*)(bias + lane * 4);
    acc.x += b.x; acc.y += b.y; acc.z += b.z; acc.w += b.w;
    *(float4*)(out + (size_t)node * D + lane * 4) = acc;
}

extern "C" void kernel_launch(void* const* d_in, const int* in_sizes, int n_in,
                              void* d_out, int out_size, void* d_ws, size_t ws_size,
                              hipStream_t stream) {
    const float* X    = (const float*)d_in[0];
    const int*   erow = (const int*)d_in[1];
    const int*   ecol = (const int*)d_in[2];
    const float* eval = (const float*)d_in[3];
    const float* W    = (const float*)d_in[4];
    const float* bias = (const float*)d_in[5];
    float* out = (float*)d_out;

    const int M = in_sizes[0] / D;   // 100000
    const int E = in_sizes[1];       // 1600000
    const int NB = (M + 255) / 256;  // 391

    // workspace carve (~117 MB)
    char* p = (char*)d_ws;
    unsigned short* Xb  = (unsigned short*)p; p += (size_t)M * D * sizeof(unsigned short);
    unsigned short* XWb = (unsigned short*)p; p += (size_t)M * D * sizeof(unsigned short);
    unsigned short* Wt  = (unsigned short*)p; p += (size_t)D * D * sizeof(unsigned short);
    int* counts = (int*)p;      p += (size_t)M * sizeof(int);
    int* offsets = (int*)p;     p += (size_t)(M + 1) * sizeof(int);
    int* cursor = (int*)p;      p += (size_t)M * sizeof(int);
    int* partials = (int*)p;    p += (size_t)NB * sizeof(int);
    p = (char*)(((uintptr_t)p + 15) & ~(uintptr_t)15);
    int* scol = (int*)p;        p += (size_t)E * sizeof(int);
    float* sval = (float*)p;    p += (size_t)E * sizeof(float);

    hipMemsetAsync(counts, 0, (size_t)M * sizeof(int), stream);
    hist_kernel<<<(E + 255) / 256, 256, 0, stream>>>(erow, counts, E);
    block_sums_kernel<<<NB, 256, 0, stream>>>(counts, partials, M);
    scan_partials_kernel<<<1, 256, 0, stream>>>(partials, NB);
    scan_local_kernel<<<NB, 256, 0, stream>>>(counts, partials, offsets, cursor, M);
    permute_kernel<<<(E + 255) / 256, 256, 0, stream>>>(erow, ecol, eval, cursor, scol, sval, E);

    convert_x_kernel<<<(M * D / 4 + 255) / 256, 256, 0, stream>>>(X, Xb, M * D / 4);
    convert_wt_kernel<<<(D * D) / 256, 256, 0, stream>>>(W, Wt);

    dim3 ggrid((M + 127) / 128, D / 128);
    gemm_mfma_kernel<<<ggrid, 256, 0, stream>>>(Xb, Wt, XWb, M);

    gather_kernel<<<(int)(((size_t)M * 64 + 255) / 256), 256, 0, stream>>>(
        XWb, offsets, scol, sval, bias, out, M);
}